// Round 15
// baseline (514.294 us; speedup 1.0000x reference)
//
#include <hip/hip_runtime.h>

#define TPB 256
#define CAP 9216       // per-bucket capacity (mean 8184, sigma ~90 -> +11 sigma)
#define EPB 4096       // edges per block in k_bucket (16/thread)
#define OFSW 784       // ofs table row stride (>= NB+1, 16-aligned)
#define GBPAD 784      // ofsT row stride (>= gB, 16-aligned)

typedef float f32x4 __attribute__((ext_vector_type(4)));
typedef float f32x2 __attribute__((ext_vector_type(2)));
typedef unsigned u32x4 __attribute__((ext_vector_type(4)));

__device__ __forceinline__ float lrelu(float x) { return x > 0.f ? x : 0.2f * x; }

// bf16 helpers (RNE pack)
__device__ __forceinline__ unsigned bfr(float x) {
  unsigned u = __float_as_uint(x);
  return (u + 0x7FFFu + ((u >> 16) & 1u)) >> 16;
}
__device__ __forceinline__ unsigned pk(float a, float b) { return bfr(a) | (bfr(b) << 16); }
__device__ __forceinline__ float ubf(unsigned us) { return __uint_as_float(us << 16); }

// ============================ bucketed CSR build ============================
__global__ void __launch_bounds__(TPB) k_bucket(
    const int* __restrict__ ei, int E, int N,
    unsigned* __restrict__ items2, int* __restrict__ ofs)
{
  __shared__ int hist[1024];
  __shared__ int lofs[1024];
  __shared__ int scan_s[TPB];
  __shared__ unsigned stage[2 * EPB];
  int tid = threadIdx.x;
  for (int i = tid; i < 1024; i += TPB) hist[i] = 0;
  int s0 = blockIdx.x * EPB;
  int nE = min(EPB, E - s0);
  int sv[16], dv[16];
  __syncthreads();
#pragma unroll
  for (int k = 0; k < 4; k++) {
    int li = tid * 4 + k * TPB * 4;
    if (li + 3 < nE) {
      int4 s4 = *(const int4*)(ei + s0 + li);
      int4 d4 = *(const int4*)(ei + E + s0 + li);
      sv[k*4+0] = s4.x; sv[k*4+1] = s4.y; sv[k*4+2] = s4.z; sv[k*4+3] = s4.w;
      dv[k*4+0] = d4.x; dv[k*4+1] = d4.y; dv[k*4+2] = d4.z; dv[k*4+3] = d4.w;
#pragma unroll
      for (int j = 0; j < 4; j++) {
        atomicAdd(&hist[dv[k*4+j] >> 8], 1);
        atomicAdd(&hist[(N + sv[k*4+j]) >> 8], 1);
      }
    } else {
      for (int j = 0; j < 4; j++) {
        if (li + j < nE) {
          sv[k*4+j] = ei[s0 + li + j];
          dv[k*4+j] = ei[E + s0 + li + j];
          atomicAdd(&hist[dv[k*4+j] >> 8], 1);
          atomicAdd(&hist[(N + sv[k*4+j]) >> 8], 1);
        }
      }
    }
  }
  __syncthreads();
  int b0 = tid * 4;
  int c0 = hist[b0], c1 = hist[b0 + 1], c2 = hist[b0 + 2], c3 = hist[b0 + 3];
  int tsum = c0 + c1 + c2 + c3;
  scan_s[tid] = tsum;
  __syncthreads();
#pragma unroll
  for (int o = 1; o < TPB; o <<= 1) {
    int t = (tid >= o) ? scan_s[tid - o] : 0;
    __syncthreads();
    scan_s[tid] += t;
    __syncthreads();
  }
  int run = scan_s[tid] - tsum;
  int cs[4] = {c0, c1, c2, c3};
#pragma unroll
  for (int j = 0; j < 4; j++) {
    int b = b0 + j;
    lofs[b] = run;
    hist[b] = 0;
    run += cs[j];
  }
  __syncthreads();
#pragma unroll
  for (int k = 0; k < 16; k++) {
    int li = tid * 4 + (k >> 2) * TPB * 4 + (k & 3);
    if (li < nE) {
      int s = sv[k], d = dv[k];
      int b1 = d >> 8;
      int p1 = lofs[b1] + atomicAdd(&hist[b1], 1);
      stage[p1] = ((unsigned)(d & 255) << 24) | (unsigned)s;
      int k2 = N + s, b2 = k2 >> 8;
      int p2 = lofs[b2] + atomicAdd(&hist[b2], 1);
      stage[p2] = ((unsigned)(k2 & 255) << 24) | (unsigned)d;
    }
  }
  __syncthreads();
  int total = 2 * nE;
  size_t obase = (size_t)blockIdx.x * (2 * EPB);
  for (int idx = tid; idx < total; idx += TPB)
    __builtin_nontemporal_store(stage[idx], items2 + obase + idx);
  int orow = blockIdx.x * OFSW;
  for (int i = tid; i < OFSW; i += TPB)
    ofs[orow + i] = lofs[i];
}

// Tiled transpose of the ofs table.
__global__ void __launch_bounds__(TPB) k_t(
    const int* __restrict__ ofs, int* __restrict__ ofsT, int nB)
{
  __shared__ int tile[32][33];
  int lx = threadIdx.x & 31, ly = threadIdx.x >> 5;
  int b0 = blockIdx.y * 32, k0 = blockIdx.x * 32;
#pragma unroll
  for (int r = 0; r < 32; r += 8) {
    int b = b0 + ly + r, k = k0 + lx;
    tile[ly + r][lx] = (b < nB && k < OFSW) ? ofs[b * OFSW + k] : 0;
  }
  __syncthreads();
#pragma unroll
  for (int r = 0; r < 32; r += 8) {
    int k = k0 + ly + r, b = b0 + lx;
    if (k < OFSW && b < GBPAD) ofsT[k * GBPAD + b] = tile[lx][ly + r];
  }
}

// Pass 2: coalesced ofsT rows, deterministic block scan, uint4 run copies.
__global__ void __launch_bounds__(TPB) k_csr2(
    const int* __restrict__ ofsT, const unsigned* __restrict__ items2, int nB,
    unsigned* __restrict__ items, int* __restrict__ rowptr, int* __restrict__ rowend, int n2)
{
  __shared__ unsigned stage[CAP];
  __shared__ int cnt_s[TPB], scan_s[TPB], off_s[TPB];
  int tid = threadIdx.x, k = blockIdx.x;
  cnt_s[tid] = 0;
  int o0[4], cl[4];
  int tsum = 0;
#pragma unroll
  for (int m = 0; m < 4; m++) {
    int b = tid + m * TPB;
    if (b < nB) {
      int a0 = ofsT[(size_t)k * GBPAD + b];
      int a1 = ofsT[(size_t)(k + 1) * GBPAD + b];
      o0[m] = a0; cl[m] = a1 - a0;
    } else { o0[m] = 0; cl[m] = 0; }
    tsum += cl[m];
  }
  scan_s[tid] = tsum;
  __syncthreads();
#pragma unroll
  for (int o = 1; o < TPB; o <<= 1) {
    int t = (tid >= o) ? scan_s[tid - o] : 0;
    __syncthreads();
    scan_s[tid] += t;
    __syncthreads();
  }
  int cnt = min(scan_s[TPB - 1], CAP);
  int dst = scan_s[tid] - tsum;
#pragma unroll
  for (int m = 0; m < 4; m++) {
    int b = tid + m * TPB;
    const unsigned* src = items2 + (size_t)b * (2 * EPB) + o0[m];
    int c = cl[m];
    int j = 0;
    int head = (4 - (o0[m] & 3)) & 3; if (head > c) head = c;
    for (; j < head; j++) { int p = dst + j; if (p < CAP) stage[p] = src[j]; }
    for (; j + 3 < c; j += 4) {
      u32x4 v = *(const u32x4*)(src + j);
      int p = dst + j;
      if (p + 3 < CAP) {
        stage[p] = v.x; stage[p+1] = v.y; stage[p+2] = v.z; stage[p+3] = v.w;
      } else {
        if (p < CAP) stage[p] = v.x;
        if (p+1 < CAP) stage[p+1] = v.y;
        if (p+2 < CAP) stage[p+2] = v.z;
        if (p+3 < CAP) stage[p+3] = v.w;
      }
    }
    for (; j < c; j++) { int p = dst + j; if (p < CAP) stage[p] = src[j]; }
    dst += c;
  }
  __syncthreads();
  for (int i = tid; i < cnt; i += TPB) atomicAdd(&cnt_s[stage[i] >> 24], 1);
  __syncthreads();
  int v = cnt_s[tid];
  scan_s[tid] = v;
  __syncthreads();
#pragma unroll
  for (int o = 1; o < TPB; o <<= 1) {
    int t = (tid >= o) ? scan_s[tid - o] : 0;
    __syncthreads();
    scan_s[tid] += t;
    __syncthreads();
  }
  int excl = scan_s[tid] - v;
  off_s[tid] = excl;
  size_t bbase = (size_t)k * CAP;
  int g = k * 256 + tid;
  if (g < n2) { rowptr[g] = (int)bbase + excl; rowend[g] = (int)bbase + excl + v; }
  cnt_s[tid] = 0;
  __syncthreads();
  for (int i = tid; i < cnt; i += TPB) {
    unsigned u = stage[i];
    int kk = u >> 24;
    int r = atomicAdd(&cnt_s[kk], 1);
    items[bbase + off_s[kk] + r] = u & 0xFFFFFFu;
  }
}

// ============================ dense node kernels ============================
// 40 B packed records: u0=bf16 es[0..1], u1=bf16 es[2..3],
// u[2+2h]/u[3+2h]=bf16 h[h][0..3].  rec3: 32 B = 2 x {f32 es, 4 bf16 h}.

__global__ void __launch_bounds__(TPB) k_score(
    const float* __restrict__ x1, const float* __restrict__ x2,
    const float* __restrict__ Wq, const float* __restrict__ bq,
    const float* __restrict__ Wk, const float* __restrict__ bk,
    float* __restrict__ escore, float* __restrict__ sumexp, int N)
{
  __shared__ float sWq[128], sWk[160], sbq[16], sbk[16];
  for (int i = threadIdx.x; i < 128; i += TPB) sWq[i] = Wq[i];
  for (int i = threadIdx.x; i < 160; i += TPB) sWk[i] = Wk[i];
  if (threadIdx.x < 16) { sbq[threadIdx.x] = bq[threadIdx.x]; sbk[threadIdx.x] = bk[threadIdx.x]; }
  __syncthreads();
  int n = blockIdx.x * TPB + threadIdx.x;
  float e = 0.f;
  if (n < N) {
    float a[8], b[10];
#pragma unroll
    for (int i = 0; i < 8; i++) a[i] = x1[n*8 + i];
#pragma unroll
    for (int i = 0; i < 10; i++) b[i] = x2[n*10 + i];
    float score = 0.f;
#pragma unroll
    for (int j = 0; j < 16; j++) {
      float q = sbq[j], k = sbk[j];
#pragma unroll
      for (int i = 0; i < 8; i++) q += a[i] * sWq[i*16 + j];
#pragma unroll
      for (int i = 0; i < 10; i++) k += b[i] * sWk[i*16 + j];
      score += q * k;
    }
    e = __expf(score);   // |score| small: exp safe without max-subtraction
    escore[n] = e;
  }
  float v = e;
#pragma unroll
  for (int off = 32; off > 0; off >>= 1) v += __shfl_down(v, off);
  __shared__ float red[TPB / 64];
  if ((threadIdx.x & 63) == 0) red[threadIdx.x >> 6] = v;
  __syncthreads();
  if (threadIdx.x == 0) {
    float s = 0.f;
#pragma unroll
    for (int w = 0; w < TPB / 64; w++) s += red[w];
    atomicAdd(sumexp, s);
  }
}

__global__ void __launch_bounds__(TPB) k_A1(
    const float* __restrict__ x1, const float* __restrict__ x2,
    const float* __restrict__ Wv, const float* __restrict__ bv,
    const float* __restrict__ W1, const float* __restrict__ a1s, const float* __restrict__ a1d,
    const float* __restrict__ escore, const float* __restrict__ sumexp,
    unsigned* __restrict__ rec1a, unsigned* __restrict__ rec1b,
    float* __restrict__ ed, int N)
{
  __shared__ float sWv[288], sbv[16], sW1[512], sas[32], sad[32];
  for (int i = threadIdx.x; i < 288; i += TPB) sWv[i] = Wv[i];
  for (int i = threadIdx.x; i < 512; i += TPB) sW1[i] = W1[i];
  if (threadIdx.x < 16) sbv[threadIdx.x] = bv[threadIdx.x];
  if (threadIdx.x < 32) { sas[threadIdx.x] = a1s[threadIdx.x]; sad[threadIdx.x] = a1d[threadIdx.x]; }
  __syncthreads();
  int n = blockIdx.x * TPB + threadIdx.x;
  if (n >= N) return;
  float w = escore[n] / sumexp[0];
  float f[16];
  {
    float a[8], b[10];
#pragma unroll
    for (int i = 0; i < 8; i++) a[i] = x1[n*8 + i];
#pragma unroll
    for (int i = 0; i < 10; i++) b[i] = x2[n*10 + i];
#pragma unroll
    for (int j = 0; j < 16; j++) {
      float v = sbv[j];
#pragma unroll
      for (int i = 0; i < 8; i++) v += a[i] * sWv[i*16 + j];
#pragma unroll
      for (int i = 0; i < 10; i++) v += b[i] * sWv[(8 + i)*16 + j];
      f[j] = w * v;
    }
  }
  float hr[32], esv[8], edv[8];
#pragma unroll
  for (int j = 0; j < 32; j++) {
    float s = 0.f;
#pragma unroll
    for (int i = 0; i < 16; i++) s += f[i] * sW1[i*32 + j];
    hr[j] = s;
  }
#pragma unroll
  for (int hh = 0; hh < 8; hh++) {
    float s = 0.f, d = 0.f;
#pragma unroll
    for (int c = 0; c < 4; c++) { s += hr[hh*4+c]*sas[hh*4+c]; d += hr[hh*4+c]*sad[hh*4+c]; }
    esv[hh] = s; edv[hh] = d;
  }
  unsigned* ra = rec1a + (size_t)n*10;
  unsigned* rb = rec1b + (size_t)n*10;
  ra[0] = pk(esv[0], esv[1]); ra[1] = pk(esv[2], esv[3]);
  rb[0] = pk(esv[4], esv[5]); rb[1] = pk(esv[6], esv[7]);
#pragma unroll
  for (int hh = 0; hh < 4; hh++) {
    ra[2+2*hh] = pk(hr[hh*4+0], hr[hh*4+1]);
    ra[3+2*hh] = pk(hr[hh*4+2], hr[hh*4+3]);
    rb[2+2*hh] = pk(hr[16+hh*4+0], hr[16+hh*4+1]);
    rb[3+2*hh] = pk(hr[16+hh*4+2], hr[16+hh*4+3]);
  }
  f32x4 e0 = {edv[0], edv[1], edv[2], edv[3]};
  f32x4 e1 = {edv[4], edv[5], edv[6], edv[7]};
  *(f32x4*)(ed + n*8)     = e0;
  *(f32x4*)(ed + n*8 + 4) = e1;
}

// ==================== wave-per-row gather passes ============================
// Layer 1 pass a (heads 0-3): gather rec1a, write X[d*16 + hh*4] (biased).
__global__ void __launch_bounds__(TPB) k_gat1a(
    const int* __restrict__ rowptr, const int* __restrict__ rowend, const int* __restrict__ col,
    const unsigned* __restrict__ rec, const float* __restrict__ ed,
    const float* __restrict__ b1, float* __restrict__ X, int N)
{
  int wave = (blockIdx.x * TPB + threadIdx.x) >> 6;
  if (wave >= N) return;
  int lane = threadIdx.x & 63;
  int hh = lane & 3, j = lane >> 2;
  int d = wave;
  int e0 = rowptr[d], deg = rowend[d] - e0;
  float edv = ed[d*8 + hh];
  float z = 0.f;
  f32x4 acc = {0.f, 0.f, 0.f, 0.f};
  for (int t = j; t <= deg; t += 16) {
    int s = (t == deg) ? d : __builtin_nontemporal_load(col + e0 + t);
    const unsigned* rp = rec + (size_t)s*10;
    unsigned ew = rp[hh >> 1];
    uint2 hv = *(const uint2*)(rp + 2 + 2*hh);
    float esv = ubf((ew >> ((hh & 1) * 16)) & 0xFFFFu);
    float w = __expf(lrelu(esv + edv));
    z += w;
    acc.x += w * ubf(hv.x & 0xFFFFu); acc.y += w * ubf(hv.x >> 16);
    acc.z += w * ubf(hv.y & 0xFFFFu); acc.w += w * ubf(hv.y >> 16);
  }
#pragma unroll
  for (int m = 4; m < 64; m <<= 1) {
    z += __shfl_xor(z, m);
    acc.x += __shfl_xor(acc.x, m); acc.y += __shfl_xor(acc.y, m);
    acc.z += __shfl_xor(acc.z, m); acc.w += __shfl_xor(acc.w, m);
  }
  if (j == 0) {
    float inv = 1.f / z;
    const f32x4 bb = *(const f32x4*)(b1 + hh*4);
    f32x4 o = { acc.x*inv + bb.x, acc.y*inv + bb.y, acc.z*inv + bb.z, acc.w*inv + bb.w };
    __builtin_nontemporal_store(o, (f32x4*)(X + (size_t)d*16 + hh*4));
  }
}

// Layer 1 pass b (heads 4-7) + FUSED B2: gather rec1b; epilogue computes
// h2 = Xrow(32)@W2 via shuffle-GEMV (Xrow[0..15] from X, [16..31] from regs),
// then rec2 (40 B) + layer-2 ed. No X[16..31] round trip.
__global__ void __launch_bounds__(TPB) k_gat1b(
    const int* __restrict__ rowptr, const int* __restrict__ rowend, const int* __restrict__ col,
    const unsigned* __restrict__ rec, const float* __restrict__ ed_rw,
    const float* __restrict__ b1, const float* __restrict__ X,
    const float* __restrict__ W2, const float* __restrict__ a2s, const float* __restrict__ a2d,
    unsigned* __restrict__ rec2, float* __restrict__ edw, int N)
{
  __shared__ float sW2[512], sas2[16], sad2[16];
  for (int i = threadIdx.x; i < 512; i += TPB) sW2[i] = W2[i];
  if (threadIdx.x < 16) { sas2[threadIdx.x] = a2s[threadIdx.x]; sad2[threadIdx.x] = a2d[threadIdx.x]; }
  __syncthreads();
  int wave = (blockIdx.x * TPB + threadIdx.x) >> 6;
  if (wave >= N) return;
  int lane = threadIdx.x & 63;
  int hh = lane & 3, j = lane >> 2;
  int d = wave;
  int e0 = rowptr[d], deg = rowend[d] - e0;
  float edv = ed_rw[d*8 + 4 + hh];
  float z = 0.f;
  f32x4 acc = {0.f, 0.f, 0.f, 0.f};
  for (int t = j; t <= deg; t += 16) {
    int s = (t == deg) ? d : __builtin_nontemporal_load(col + e0 + t);
    const unsigned* rp = rec + (size_t)s*10;
    unsigned ew = rp[hh >> 1];
    uint2 hv = *(const uint2*)(rp + 2 + 2*hh);
    float esv = ubf((ew >> ((hh & 1) * 16)) & 0xFFFFu);
    float w = __expf(lrelu(esv + edv));
    z += w;
    acc.x += w * ubf(hv.x & 0xFFFFu); acc.y += w * ubf(hv.x >> 16);
    acc.z += w * ubf(hv.y & 0xFFFFu); acc.w += w * ubf(hv.y >> 16);
  }
#pragma unroll
  for (int m = 4; m < 64; m <<= 1) {
    z += __shfl_xor(z, m);
    acc.x += __shfl_xor(acc.x, m); acc.y += __shfl_xor(acc.y, m);
    acc.z += __shfl_xor(acc.z, m); acc.w += __shfl_xor(acc.w, m);
  }
  // all lanes: o = this row's head (4+hh) output, biased (uniform across j)
  float inv = 1.f / z;
  const f32x4 bb = *(const f32x4*)(b1 + (4 + hh)*4);
  f32x4 o = { acc.x*inv + bb.x, acc.y*inv + bb.y, acc.z*inv + bb.z, acc.w*inv + bb.w };
  // --- fused B2 ---
  float xpart = 0.f;
  if (lane < 16) xpart = X[(size_t)d*16 + lane];
  float h2 = 0.f;
#pragma unroll
  for (int f = 0; f < 16; f++) {
    float xv = __shfl(xpart, f);
    if (lane < 16) h2 += xv * sW2[f*16 + lane];
  }
#pragma unroll
  for (int hq = 0; hq < 4; hq++) {
    float v0 = __shfl(o.x, hq), v1 = __shfl(o.y, hq);
    float v2 = __shfl(o.z, hq), v3 = __shfl(o.w, hq);
    if (lane < 16) {
      h2 += v0 * sW2[(16 + hq*4 + 0)*16 + lane];
      h2 += v1 * sW2[(16 + hq*4 + 1)*16 + lane];
      h2 += v2 * sW2[(16 + hq*4 + 2)*16 + lane];
      h2 += v3 * sW2[(16 + hq*4 + 3)*16 + lane];
    }
  }
  float p_s = 0.f, p_d = 0.f;
  if (lane < 16) { p_s = h2 * sas2[lane]; p_d = h2 * sad2[lane]; }
  p_s += __shfl_xor(p_s, 1); p_s += __shfl_xor(p_s, 2);
  p_d += __shfl_xor(p_d, 1); p_d += __shfl_xor(p_d, 2);
  // writes (shuffles executed by all lanes; stores predicated)
  unsigned* r2 = rec2 + (size_t)d*10;
  float ha = __shfl(h2, (lane & 7)*2), hb = __shfl(h2, (lane & 7)*2 + 1);
  unsigned upk = pk(ha, hb);
  if (lane < 8) r2[2 + lane] = upk;
  float es0 = __shfl(p_s, 0), es1 = __shfl(p_s, 4);
  float es2v = __shfl(p_s, 8), es3v = __shfl(p_s, 12);
  if (lane == 8) { r2[0] = pk(es0, es1); r2[1] = pk(es2v, es3v); }
  float edsel = __shfl(p_d, (lane & 3)*4);
  if (lane < 4) edw[d*8 + lane] = edsel;
}

// Layer 2 gather (heads 0-3 of rec2) + FUSED B3: the wave's 4 reduced heads
// ARE the full X3 row; shuffle-GEMV -> rec3 (32 B) + layer-3 ed. X3 never hits memory.
__global__ void __launch_bounds__(TPB) k_gat2f(
    const int* __restrict__ rowptr, const int* __restrict__ rowend, const int* __restrict__ col,
    const unsigned* __restrict__ rec, const float* __restrict__ ed_rw,
    const float* __restrict__ b2,
    const float* __restrict__ W3, const float* __restrict__ a3s, const float* __restrict__ a3d,
    unsigned* __restrict__ rec3, float* __restrict__ edw, int N)
{
  __shared__ float sW3[128], sas3[8], sad3[8];
  for (int i = threadIdx.x; i < 128; i += TPB) sW3[i] = W3[i];
  if (threadIdx.x < 8) { sas3[threadIdx.x] = a3s[threadIdx.x]; sad3[threadIdx.x] = a3d[threadIdx.x]; }
  __syncthreads();
  int wave = (blockIdx.x * TPB + threadIdx.x) >> 6;
  if (wave >= N) return;
  int lane = threadIdx.x & 63;
  int hh = lane & 3, j = lane >> 2;
  int d = wave;
  int e0 = rowptr[d], deg = rowend[d] - e0;
  float edv = ed_rw[d*8 + hh];
  float z = 0.f;
  f32x4 acc = {0.f, 0.f, 0.f, 0.f};
  for (int t = j; t <= deg; t += 16) {
    int s = (t == deg) ? d : __builtin_nontemporal_load(col + e0 + t);
    const unsigned* rp = rec + (size_t)s*10;
    unsigned ew = rp[hh >> 1];
    uint2 hv = *(const uint2*)(rp + 2 + 2*hh);
    float esv = ubf((ew >> ((hh & 1) * 16)) & 0xFFFFu);
    float w = __expf(lrelu(esv + edv));
    z += w;
    acc.x += w * ubf(hv.x & 0xFFFFu); acc.y += w * ubf(hv.x >> 16);
    acc.z += w * ubf(hv.y & 0xFFFFu); acc.w += w * ubf(hv.y >> 16);
  }
#pragma unroll
  for (int m = 4; m < 64; m <<= 1) {
    z += __shfl_xor(z, m);
    acc.x += __shfl_xor(acc.x, m); acc.y += __shfl_xor(acc.y, m);
    acc.z += __shfl_xor(acc.z, m); acc.w += __shfl_xor(acc.w, m);
  }
  float inv = 1.f / z;
  const f32x4 bb = *(const f32x4*)(b2 + hh*4);
  f32x4 o = { acc.x*inv + bb.x, acc.y*inv + bb.y, acc.z*inv + bb.z, acc.w*inv + bb.w };
  // --- fused B3: h3[l] (l<8) = sum_f X3[f]*W3[f*8+l], X3[f] = comp f&3 of lane f>>2 ---
  float h3 = 0.f;
#pragma unroll
  for (int hq = 0; hq < 4; hq++) {
    float v0 = __shfl(o.x, hq), v1 = __shfl(o.y, hq);
    float v2 = __shfl(o.z, hq), v3 = __shfl(o.w, hq);
    if (lane < 8) {
      h3 += v0 * sW3[(hq*4 + 0)*8 + lane];
      h3 += v1 * sW3[(hq*4 + 1)*8 + lane];
      h3 += v2 * sW3[(hq*4 + 2)*8 + lane];
      h3 += v3 * sW3[(hq*4 + 3)*8 + lane];
    }
  }
  float p_s = 0.f, p_d = 0.f;
  if (lane < 8) { p_s = h3 * sas3[lane]; p_d = h3 * sad3[lane]; }
  p_s += __shfl_xor(p_s, 1); p_s += __shfl_xor(p_s, 2);
  p_d += __shfl_xor(p_d, 1); p_d += __shfl_xor(p_d, 2);
  float esh = __shfl(p_s, (lane & 1)*4);
  float h0 = __shfl(h3, (lane & 1)*4 + 0), h1 = __shfl(h3, (lane & 1)*4 + 1);
  float h2v = __shfl(h3, (lane & 1)*4 + 2), h3v = __shfl(h3, (lane & 1)*4 + 3);
  if (lane < 2) {
    u32x4 q = { __float_as_uint(esh), pk(h0, h1), pk(h2v, h3v), 0u };
    __builtin_nontemporal_store(q, (u32x4*)(rec3 + (size_t)d*8 + lane*4));
  }
  float edh = __shfl(p_d, (lane & 1)*4);
  if (lane < 2) edw[d*8 + lane] = edh;
}

// Layer 3: 2 heads x 32 slots; 32 B records, 1 uint4 load.
__global__ void __launch_bounds__(TPB) k_gat3(
    const int* __restrict__ rowptr, const int* __restrict__ rowend, const int* __restrict__ col,
    const unsigned* __restrict__ rec, const float* __restrict__ ed,
    const float* __restrict__ b3, float* __restrict__ x4, int N)
{
  int wave = (blockIdx.x * TPB + threadIdx.x) >> 6;
  if (wave >= N) return;
  int lane = threadIdx.x & 63;
  int hh = lane & 1, j = lane >> 1;
  int d = wave;
  int e0 = rowptr[d], deg = rowend[d] - e0;
  float edv = ed[d*8 + hh];
  float z = 0.f;
  f32x4 acc = {0.f, 0.f, 0.f, 0.f};
  for (int t = j; t <= deg; t += 32) {
    int s = (t == deg) ? d : __builtin_nontemporal_load(col + e0 + t);
    u32x4 q = *(const u32x4*)(rec + (size_t)s*8 + hh*4);
    float w = __expf(lrelu(__uint_as_float(q.x) + edv));
    z += w;
    acc.x += w * ubf(q.y & 0xFFFFu); acc.y += w * ubf(q.y >> 16);
    acc.z += w * ubf(q.z & 0xFFFFu); acc.w += w * ubf(q.z >> 16);
  }
#pragma unroll
  for (int m = 2; m < 64; m <<= 1) {
    z += __shfl_xor(z, m);
    acc.x += __shfl_xor(acc.x, m); acc.y += __shfl_xor(acc.y, m);
    acc.z += __shfl_xor(acc.z, m); acc.w += __shfl_xor(acc.w, m);
  }
  if (j == 0) {
    float inv = 1.f / z;
    const f32x4 bb = *(const f32x4*)(b3 + hh*4);
    f32x4 o = { acc.x*inv + bb.x, acc.y*inv + bb.y, acc.z*inv + bb.z, acc.w*inv + bb.w };
    __builtin_nontemporal_store(o, (f32x4*)(x4 + d*8 + hh*4));
  }
}

__global__ void __launch_bounds__(TPB) k_adj_final(
    const int* __restrict__ rowptr, const int* __restrict__ rowend, const int* __restrict__ col,
    const float* __restrict__ x4, const float* __restrict__ Wl2,
    float* __restrict__ out, int N)
{
  __shared__ float sW[8];
  if (threadIdx.x < 8) sW[threadIdx.x] = Wl2[threadIdx.x];
  __syncthreads();
  int wave = (blockIdx.x * TPB + threadIdx.x) >> 6;
  if (wave >= N) return;
  int lane = threadIdx.x & 63;
  int q = lane & 1, j = lane >> 1;
  int r = wave;
  int e0 = rowptr[N + r], deg = rowend[N + r] - e0;
  f32x4 acc = {0.f, 0.f, 0.f, 0.f};
  for (int t = j; t < deg; t += 32) {
    int c = __builtin_nontemporal_load(col + e0 + t);
    f32x4 xv = *(const f32x4*)(x4 + c*8 + q*4);
    acc.x += xv.x; acc.y += xv.y; acc.z += xv.z; acc.w += xv.w;
  }
#pragma unroll
  for (int m = 2; m < 64; m <<= 1) {
    acc.x += __shfl_xor(acc.x, m); acc.y += __shfl_xor(acc.y, m);
    acc.z += __shfl_xor(acc.z, m); acc.w += __shfl_xor(acc.w, m);
  }
  float part = 0.f;
  if (j == 0) {
    float inv = deg > 0 ? 1.f / (float)deg : 0.f;
    f32x4 R = { acc.x*inv, acc.y*inv, acc.z*inv, acc.w*inv };
    f32x4 xo = *(const f32x4*)(x4 + r*8 + q*4);
    part = xo.x*R.x + xo.y*R.y + xo.z*R.z + xo.w*R.w
         + R.x*sW[q*4+0] + R.y*sW[q*4+1] + R.z*sW[q*4+2] + R.w*sW[q*4+3];
  }
  part += __shfl_xor(part, 1);
  if (lane == 0) out[r] = part;
}

// ============================ launch ========================================
extern "C" void kernel_launch(void* const* d_in, const int* in_sizes, int n_in,
                              void* d_out, int out_size, void* d_ws, size_t ws_size,
                              hipStream_t stream)
{
  const float* x1  = (const float*)d_in[0];
  const float* x2  = (const float*)d_in[1];
  const int*   ei  = (const int*)d_in[2];
  const float* Wq  = (const float*)d_in[4];
  const float* bq  = (const float*)d_in[5];
  const float* Wk  = (const float*)d_in[6];
  const float* bk  = (const float*)d_in[7];
  const float* Wv  = (const float*)d_in[8];
  const float* bv  = (const float*)d_in[9];
  const float* W1  = (const float*)d_in[10];
  const float* a1s = (const float*)d_in[11];
  const float* a1d = (const float*)d_in[12];
  const float* b1  = (const float*)d_in[13];
  const float* W2  = (const float*)d_in[14];
  const float* a2s = (const float*)d_in[15];
  const float* a2d = (const float*)d_in[16];
  const float* b2  = (const float*)d_in[17];
  const float* W3  = (const float*)d_in[18];
  const float* a3s = (const float*)d_in[19];
  const float* a3d = (const float*)d_in[20];
  const float* b3  = (const float*)d_in[21];
  const float* Wl2 = (const float*)d_in[22];

  int N = in_sizes[0] / 8;
  int E = in_sizes[2] / 2;
  int n2 = 2 * N;
  int NB = (n2 + 255) >> 8;             // CSR buckets (782)
  int gB = (E + EPB - 1) / EPB;         // k_bucket blocks (782)

  // ---- workspace ----
  float* sumexp = (float*)d_ws;                          // 16 (1 used, zeroed)
  int* rowptr   = (int*)(sumexp + 16);                   // 2N
  int* rowend   = rowptr + (size_t)n2;                   // 2N
  unsigned* itemsCSR = (unsigned*)(rowend + (size_t)n2); // NB*CAP (28.8 MB)
  unsigned* regionA  = itemsCSR + (size_t)NB * CAP;
  // phase 1 (CSR build): items2 + ofs + ofsT live in regionA
  unsigned* items2 = regionA;                            // gB*8192 (25.6 MB)
  int* ofs  = (int*)(items2 + (size_t)gB * (2 * EPB));   // gB*OFSW
  int* ofsT = ofs + (size_t)gB * OFSW;                   // OFSW*GBPAD
  size_t raSize = (size_t)gB * (2 * EPB + OFSW) + (size_t)OFSW * GBPAD;
  // phase 2: recs/ed/escore alias regionA. 10N+10N+10N+8N+8N+N = 47N < raSize ✓
  unsigned* rec1a = regionA;                             // 10N (4.0 MB, L2-resident)
  unsigned* rec1b = rec1a + 10ull*N;                     // 10N (aliased by x4 later)
  unsigned* rec2  = rec1b + 10ull*N;                     // 10N
  unsigned* rec3  = rec2 + 10ull*N;                      // 8N (3.2 MB)
  float* ed       = (float*)(rec3 + 8ull*N);             // 8N
  float* escore   = ed + 8ull*N;                         // N
  float* X        = (float*)(regionA + raSize);          // 16N (heads 0-3 only)
  float* x4 = (float*)rec1b;                             // 8N (rec1b dead after k_gat1b)

  int gN = (N + TPB - 1) / TPB;
  int g64 = (int)(((long long)N * 64 + TPB - 1) / TPB);  // wave-per-row grids

  (void)hipMemsetAsync(sumexp, 0, 16 * sizeof(float), stream);

  // CSR build
  k_bucket<<<gB, TPB, 0, stream>>>(ei, E, N, items2, ofs);
  dim3 gt((OFSW + 31) / 32, (gB + 31) / 32);
  k_t<<<gt, TPB, 0, stream>>>(ofs, ofsT, gB);
  k_csr2<<<NB, TPB, 0, stream>>>(ofsT, items2, gB, itemsCSR, rowptr, rowend, n2);
  int* colv = (int*)itemsCSR;

  // dense prologue
  k_score<<<gN, TPB, 0, stream>>>(x1, x2, Wq, bq, Wk, bk, escore, sumexp, N);
  k_A1<<<gN, TPB, 0, stream>>>(x1, x2, Wv, bv, W1, a1s, a1d, escore, sumexp, rec1a, rec1b, ed, N);

  // GAT layer 1 pass a (heads 0-3 -> X), pass b (heads 4-7, fused B2 -> rec2/ed)
  k_gat1a<<<g64, TPB, 0, stream>>>(rowptr, rowend, colv, rec1a, ed, b1, X, N);
  k_gat1b<<<g64, TPB, 0, stream>>>(rowptr, rowend, colv, rec1b, ed, b1, X,
                                   W2, a2s, a2d, rec2, ed, N);
  // GAT layer 2 (fused B3 -> rec3/ed)
  k_gat2f<<<g64, TPB, 0, stream>>>(rowptr, rowend, colv, rec2, ed, b2,
                                   W3, a3s, a3d, rec3, ed, N);
  // GAT layer 3
  k_gat3<<<g64, TPB, 0, stream>>>(rowptr, rowend, colv, rec3, ed, b3, x4, N);

  // adjacency readout (src-CSR rows [N,2N))
  k_adj_final<<<g64, TPB, 0, stream>>>(rowptr, rowend, colv, x4, Wl2, (float*)d_out, N);
}

// Round 16
// 472.850 us; speedup vs baseline: 1.0876x; 1.0876x over previous
//
#include <hip/hip_runtime.h>

#define TPB 256
#define CAP 9216       // per-bucket capacity (mean 8184, sigma ~90 -> +11 sigma)
#define EPB 4096       // edges per block in k_bucket (16/thread)
#define OFSW 784       // ofs table row stride (>= NB+1, 16-aligned)
#define GBPAD 784      // ofsT row stride (>= gB, 16-aligned)

typedef float f32x4 __attribute__((ext_vector_type(4)));
typedef float f32x2 __attribute__((ext_vector_type(2)));
typedef unsigned u32x4 __attribute__((ext_vector_type(4)));

__device__ __forceinline__ float lrelu(float x) { return x > 0.f ? x : 0.2f * x; }

// bf16 helpers (RNE pack)
__device__ __forceinline__ unsigned bfr(float x) {
  unsigned u = __float_as_uint(x);
  return (u + 0x7FFFu + ((u >> 16) & 1u)) >> 16;
}
__device__ __forceinline__ unsigned pk(float a, float b) { return bfr(a) | (bfr(b) << 16); }
__device__ __forceinline__ float ubf(unsigned us) { return __uint_as_float(us << 16); }

// ============================ bucketed CSR build ============================
__global__ void __launch_bounds__(TPB) k_bucket(
    const int* __restrict__ ei, int E, int N,
    unsigned* __restrict__ items2, int* __restrict__ ofs)
{
  __shared__ int hist[1024];
  __shared__ int lofs[1024];
  __shared__ int scan_s[TPB];
  __shared__ unsigned stage[2 * EPB];
  int tid = threadIdx.x;
  for (int i = tid; i < 1024; i += TPB) hist[i] = 0;
  int s0 = blockIdx.x * EPB;
  int nE = min(EPB, E - s0);
  int sv[16], dv[16];
  __syncthreads();
#pragma unroll
  for (int k = 0; k < 4; k++) {
    int li = tid * 4 + k * TPB * 4;
    if (li + 3 < nE) {
      int4 s4 = *(const int4*)(ei + s0 + li);
      int4 d4 = *(const int4*)(ei + E + s0 + li);
      sv[k*4+0] = s4.x; sv[k*4+1] = s4.y; sv[k*4+2] = s4.z; sv[k*4+3] = s4.w;
      dv[k*4+0] = d4.x; dv[k*4+1] = d4.y; dv[k*4+2] = d4.z; dv[k*4+3] = d4.w;
#pragma unroll
      for (int j = 0; j < 4; j++) {
        atomicAdd(&hist[dv[k*4+j] >> 8], 1);
        atomicAdd(&hist[(N + sv[k*4+j]) >> 8], 1);
      }
    } else {
      for (int j = 0; j < 4; j++) {
        if (li + j < nE) {
          sv[k*4+j] = ei[s0 + li + j];
          dv[k*4+j] = ei[E + s0 + li + j];
          atomicAdd(&hist[dv[k*4+j] >> 8], 1);
          atomicAdd(&hist[(N + sv[k*4+j]) >> 8], 1);
        }
      }
    }
  }
  __syncthreads();
  int b0 = tid * 4;
  int c0 = hist[b0], c1 = hist[b0 + 1], c2 = hist[b0 + 2], c3 = hist[b0 + 3];
  int tsum = c0 + c1 + c2 + c3;
  scan_s[tid] = tsum;
  __syncthreads();
#pragma unroll
  for (int o = 1; o < TPB; o <<= 1) {
    int t = (tid >= o) ? scan_s[tid - o] : 0;
    __syncthreads();
    scan_s[tid] += t;
    __syncthreads();
  }
  int run = scan_s[tid] - tsum;
  int cs[4] = {c0, c1, c2, c3};
#pragma unroll
  for (int j = 0; j < 4; j++) {
    int b = b0 + j;
    lofs[b] = run;
    hist[b] = 0;
    run += cs[j];
  }
  __syncthreads();
#pragma unroll
  for (int k = 0; k < 16; k++) {
    int li = tid * 4 + (k >> 2) * TPB * 4 + (k & 3);
    if (li < nE) {
      int s = sv[k], d = dv[k];
      int b1 = d >> 8;
      int p1 = lofs[b1] + atomicAdd(&hist[b1], 1);
      stage[p1] = ((unsigned)(d & 255) << 24) | (unsigned)s;
      int k2 = N + s, b2 = k2 >> 8;
      int p2 = lofs[b2] + atomicAdd(&hist[b2], 1);
      stage[p2] = ((unsigned)(k2 & 255) << 24) | (unsigned)d;
    }
  }
  __syncthreads();
  int total = 2 * nE;
  size_t obase = (size_t)blockIdx.x * (2 * EPB);
  for (int idx = tid; idx < total; idx += TPB)
    __builtin_nontemporal_store(stage[idx], items2 + obase + idx);
  int orow = blockIdx.x * OFSW;
  for (int i = tid; i < OFSW; i += TPB)
    ofs[orow + i] = lofs[i];
}

// Tiled transpose of the ofs table.
__global__ void __launch_bounds__(TPB) k_t(
    const int* __restrict__ ofs, int* __restrict__ ofsT, int nB)
{
  __shared__ int tile[32][33];
  int lx = threadIdx.x & 31, ly = threadIdx.x >> 5;
  int b0 = blockIdx.y * 32, k0 = blockIdx.x * 32;
#pragma unroll
  for (int r = 0; r < 32; r += 8) {
    int b = b0 + ly + r, k = k0 + lx;
    tile[ly + r][lx] = (b < nB && k < OFSW) ? ofs[b * OFSW + k] : 0;
  }
  __syncthreads();
#pragma unroll
  for (int r = 0; r < 32; r += 8) {
    int k = k0 + ly + r, b = b0 + lx;
    if (k < OFSW && b < GBPAD) ofsT[k * GBPAD + b] = tile[lx][ly + r];
  }
}

// Pass 2: coalesced ofsT rows, deterministic block scan, uint4 run copies.
__global__ void __launch_bounds__(TPB) k_csr2(
    const int* __restrict__ ofsT, const unsigned* __restrict__ items2, int nB,
    unsigned* __restrict__ items, int* __restrict__ rowptr, int* __restrict__ rowend, int n2)
{
  __shared__ unsigned stage[CAP];
  __shared__ int cnt_s[TPB], scan_s[TPB], off_s[TPB];
  int tid = threadIdx.x, k = blockIdx.x;
  cnt_s[tid] = 0;
  int o0[4], cl[4];
  int tsum = 0;
#pragma unroll
  for (int m = 0; m < 4; m++) {
    int b = tid + m * TPB;
    if (b < nB) {
      int a0 = ofsT[(size_t)k * GBPAD + b];
      int a1 = ofsT[(size_t)(k + 1) * GBPAD + b];
      o0[m] = a0; cl[m] = a1 - a0;
    } else { o0[m] = 0; cl[m] = 0; }
    tsum += cl[m];
  }
  scan_s[tid] = tsum;
  __syncthreads();
#pragma unroll
  for (int o = 1; o < TPB; o <<= 1) {
    int t = (tid >= o) ? scan_s[tid - o] : 0;
    __syncthreads();
    scan_s[tid] += t;
    __syncthreads();
  }
  int cnt = min(scan_s[TPB - 1], CAP);
  int dst = scan_s[tid] - tsum;
#pragma unroll
  for (int m = 0; m < 4; m++) {
    int b = tid + m * TPB;
    const unsigned* src = items2 + (size_t)b * (2 * EPB) + o0[m];
    int c = cl[m];
    int j = 0;
    int head = (4 - (o0[m] & 3)) & 3; if (head > c) head = c;
    for (; j < head; j++) { int p = dst + j; if (p < CAP) stage[p] = src[j]; }
    for (; j + 3 < c; j += 4) {
      u32x4 v = *(const u32x4*)(src + j);
      int p = dst + j;
      if (p + 3 < CAP) {
        stage[p] = v.x; stage[p+1] = v.y; stage[p+2] = v.z; stage[p+3] = v.w;
      } else {
        if (p < CAP) stage[p] = v.x;
        if (p+1 < CAP) stage[p+1] = v.y;
        if (p+2 < CAP) stage[p+2] = v.z;
        if (p+3 < CAP) stage[p+3] = v.w;
      }
    }
    for (; j < c; j++) { int p = dst + j; if (p < CAP) stage[p] = src[j]; }
    dst += c;
  }
  __syncthreads();
  for (int i = tid; i < cnt; i += TPB) atomicAdd(&cnt_s[stage[i] >> 24], 1);
  __syncthreads();
  int v = cnt_s[tid];
  scan_s[tid] = v;
  __syncthreads();
#pragma unroll
  for (int o = 1; o < TPB; o <<= 1) {
    int t = (tid >= o) ? scan_s[tid - o] : 0;
    __syncthreads();
    scan_s[tid] += t;
    __syncthreads();
  }
  int excl = scan_s[tid] - v;
  off_s[tid] = excl;
  size_t bbase = (size_t)k * CAP;
  int g = k * 256 + tid;
  if (g < n2) { rowptr[g] = (int)bbase + excl; rowend[g] = (int)bbase + excl + v; }
  cnt_s[tid] = 0;
  __syncthreads();
  for (int i = tid; i < cnt; i += TPB) {
    unsigned u = stage[i];
    int kk = u >> 24;
    int r = atomicAdd(&cnt_s[kk], 1);
    items[bbase + off_s[kk] + r] = u & 0xFFFFFFu;
  }
}

// ============================ dense node kernels ============================
// 40 B packed records (L2-resident: 4.0 MB per 4-head record array):
//   u0 = bf16 es[0..1], u1 = bf16 es[2..3], u[2+2h]/u[3+2h] = bf16 h[h][0..3]

__global__ void __launch_bounds__(TPB) k_score(
    const float* __restrict__ x1, const float* __restrict__ x2,
    const float* __restrict__ Wq, const float* __restrict__ bq,
    const float* __restrict__ Wk, const float* __restrict__ bk,
    float* __restrict__ escore, float* __restrict__ sumexp, int N)
{
  __shared__ float sWq[128], sWk[160], sbq[16], sbk[16];
  for (int i = threadIdx.x; i < 128; i += TPB) sWq[i] = Wq[i];
  for (int i = threadIdx.x; i < 160; i += TPB) sWk[i] = Wk[i];
  if (threadIdx.x < 16) { sbq[threadIdx.x] = bq[threadIdx.x]; sbk[threadIdx.x] = bk[threadIdx.x]; }
  __syncthreads();
  int n = blockIdx.x * TPB + threadIdx.x;
  float e = 0.f;
  if (n < N) {
    float a[8], b[10];
#pragma unroll
    for (int i = 0; i < 8; i++) a[i] = x1[n*8 + i];
#pragma unroll
    for (int i = 0; i < 10; i++) b[i] = x2[n*10 + i];
    float score = 0.f;
#pragma unroll
    for (int j = 0; j < 16; j++) {
      float q = sbq[j], k = sbk[j];
#pragma unroll
      for (int i = 0; i < 8; i++) q += a[i] * sWq[i*16 + j];
#pragma unroll
      for (int i = 0; i < 10; i++) k += b[i] * sWk[i*16 + j];
      score += q * k;
    }
    e = __expf(score);   // |score| small: exp safe without max-subtraction
    escore[n] = e;
  }
  float v = e;
#pragma unroll
  for (int off = 32; off > 0; off >>= 1) v += __shfl_down(v, off);
  __shared__ float red[TPB / 64];
  if ((threadIdx.x & 63) == 0) red[threadIdx.x >> 6] = v;
  __syncthreads();
  if (threadIdx.x == 0) {
    float s = 0.f;
#pragma unroll
    for (int w = 0; w < TPB / 64; w++) s += red[w];
    atomicAdd(sumexp, s);
  }
}

__global__ void __launch_bounds__(TPB) k_A1(
    const float* __restrict__ x1, const float* __restrict__ x2,
    const float* __restrict__ Wv, const float* __restrict__ bv,
    const float* __restrict__ W1, const float* __restrict__ a1s, const float* __restrict__ a1d,
    const float* __restrict__ escore, const float* __restrict__ sumexp,
    unsigned* __restrict__ rec1a, unsigned* __restrict__ rec1b,
    float* __restrict__ ed, int N)
{
  __shared__ float sWv[288], sbv[16], sW1[512], sas[32], sad[32];
  for (int i = threadIdx.x; i < 288; i += TPB) sWv[i] = Wv[i];
  for (int i = threadIdx.x; i < 512; i += TPB) sW1[i] = W1[i];
  if (threadIdx.x < 16) sbv[threadIdx.x] = bv[threadIdx.x];
  if (threadIdx.x < 32) { sas[threadIdx.x] = a1s[threadIdx.x]; sad[threadIdx.x] = a1d[threadIdx.x]; }
  __syncthreads();
  int n = blockIdx.x * TPB + threadIdx.x;
  if (n >= N) return;
  float w = escore[n] / sumexp[0];
  float f[16];
  {
    float a[8], b[10];
#pragma unroll
    for (int i = 0; i < 8; i++) a[i] = x1[n*8 + i];
#pragma unroll
    for (int i = 0; i < 10; i++) b[i] = x2[n*10 + i];
#pragma unroll
    for (int j = 0; j < 16; j++) {
      float v = sbv[j];
#pragma unroll
      for (int i = 0; i < 8; i++) v += a[i] * sWv[i*16 + j];
#pragma unroll
      for (int i = 0; i < 10; i++) v += b[i] * sWv[(8 + i)*16 + j];
      f[j] = w * v;
    }
  }
  float hr[32], esv[8], edv[8];
#pragma unroll
  for (int j = 0; j < 32; j++) {
    float s = 0.f;
#pragma unroll
    for (int i = 0; i < 16; i++) s += f[i] * sW1[i*32 + j];
    hr[j] = s;
  }
#pragma unroll
  for (int hh = 0; hh < 8; hh++) {
    float s = 0.f, d = 0.f;
#pragma unroll
    for (int c = 0; c < 4; c++) { s += hr[hh*4+c]*sas[hh*4+c]; d += hr[hh*4+c]*sad[hh*4+c]; }
    esv[hh] = s; edv[hh] = d;
  }
  unsigned* ra = rec1a + (size_t)n*10;
  unsigned* rb = rec1b + (size_t)n*10;
  ra[0] = pk(esv[0], esv[1]); ra[1] = pk(esv[2], esv[3]);
  rb[0] = pk(esv[4], esv[5]); rb[1] = pk(esv[6], esv[7]);
#pragma unroll
  for (int hh = 0; hh < 4; hh++) {
    ra[2+2*hh] = pk(hr[hh*4+0], hr[hh*4+1]);
    ra[3+2*hh] = pk(hr[hh*4+2], hr[hh*4+3]);
    rb[2+2*hh] = pk(hr[16+hh*4+0], hr[16+hh*4+1]);
    rb[3+2*hh] = pk(hr[16+hh*4+2], hr[16+hh*4+3]);
  }
  f32x4 e0 = {edv[0], edv[1], edv[2], edv[3]};
  f32x4 e1 = {edv[4], edv[5], edv[6], edv[7]};
  *(f32x4*)(ed + n*8)     = e0;
  *(f32x4*)(ed + n*8 + 4) = e1;
}

__global__ void __launch_bounds__(TPB) k_B2(
    const float* __restrict__ W2, const float* __restrict__ a2s, const float* __restrict__ a2d,
    const float* __restrict__ X,
    unsigned* __restrict__ rec2, float* __restrict__ ed, int N)
{
  __shared__ float sW[512], sas[16], sad[16];
  for (int i = threadIdx.x; i < 512; i += TPB) sW[i] = W2[i];
  if (threadIdx.x < 16) { sas[threadIdx.x] = a2s[threadIdx.x]; sad[threadIdx.x] = a2d[threadIdx.x]; }
  __syncthreads();
  int n = blockIdx.x * TPB + threadIdx.x;
  if (n >= N) return;
  float Xr[32];
#pragma unroll
  for (int i = 0; i < 8; i++) {
    f32x4 t = __builtin_nontemporal_load((const f32x4*)(X + n*32) + i);
    Xr[i*4+0] = t.x; Xr[i*4+1] = t.y; Xr[i*4+2] = t.z; Xr[i*4+3] = t.w;
  }
  float hr[16];
#pragma unroll
  for (int j = 0; j < 16; j++) {
    float s = 0.f;
#pragma unroll
    for (int f = 0; f < 32; f++) s += Xr[f] * sW[f*16 + j];
    hr[j] = s;
  }
  float esv[4], edv[4];
#pragma unroll
  for (int hh = 0; hh < 4; hh++) {
    float s = 0.f, d = 0.f;
#pragma unroll
    for (int c = 0; c < 4; c++) { s += hr[hh*4+c]*sas[hh*4+c]; d += hr[hh*4+c]*sad[hh*4+c]; }
    esv[hh] = s; edv[hh] = d;
  }
  unsigned* r = rec2 + (size_t)n*10;
  r[0] = pk(esv[0], esv[1]); r[1] = pk(esv[2], esv[3]);
#pragma unroll
  for (int hh = 0; hh < 4; hh++) {
    r[2+2*hh] = pk(hr[hh*4+0], hr[hh*4+1]);
    r[3+2*hh] = pk(hr[hh*4+2], hr[hh*4+3]);
  }
  f32x4 e0 = {edv[0], edv[1], edv[2], edv[3]};
  *(f32x4*)(ed + n*8) = e0;
}

__global__ void __launch_bounds__(TPB) k_B3(
    const float* __restrict__ W3, const float* __restrict__ a3s, const float* __restrict__ a3d,
    const float* __restrict__ X3,
    unsigned* __restrict__ rec3, float* __restrict__ ed, int N)
{
  __shared__ float sW[128], sas[8], sad[8];
  for (int i = threadIdx.x; i < 128; i += TPB) sW[i] = W3[i];
  if (threadIdx.x < 8) { sas[threadIdx.x] = a3s[threadIdx.x]; sad[threadIdx.x] = a3d[threadIdx.x]; }
  __syncthreads();
  int n = blockIdx.x * TPB + threadIdx.x;
  if (n >= N) return;
  float Xr[16];
#pragma unroll
  for (int i = 0; i < 4; i++) {
    f32x4 t = __builtin_nontemporal_load((const f32x4*)(X3 + n*16) + i);
    Xr[i*4+0] = t.x; Xr[i*4+1] = t.y; Xr[i*4+2] = t.z; Xr[i*4+3] = t.w;
  }
  float hr[8];
#pragma unroll
  for (int j = 0; j < 8; j++) {
    float s = 0.f;
#pragma unroll
    for (int f = 0; f < 16; f++) s += Xr[f] * sW[f*8 + j];
    hr[j] = s;
  }
  unsigned* r = rec3 + (size_t)n*8;   // 32 B record, 2 heads x 16 B
#pragma unroll
  for (int hh = 0; hh < 2; hh++) {
    float s = 0.f, d = 0.f;
#pragma unroll
    for (int c = 0; c < 4; c++) { s += hr[hh*4+c]*sas[hh*4+c]; d += hr[hh*4+c]*sad[hh*4+c]; }
    u32x4 q = { __float_as_uint(s),
                pk(hr[hh*4+0], hr[hh*4+1]), pk(hr[hh*4+2], hr[hh*4+3]), 0u };
    __builtin_nontemporal_store(q, (u32x4*)(r + hh*4));
    ed[n*8 + hh] = d;
  }
}

// ==================== wave-per-row gather passes ============================
// 4 heads x 16 slots over 40 B L2-resident records; lane hh loads es uint +
// h uint2. Self-loop at t==deg; butterfly over slot bits.
template<int OS, int HOFF>
__global__ void __launch_bounds__(TPB) k_gat4(
    const int* __restrict__ rowptr, const int* __restrict__ rowend, const int* __restrict__ col,
    const unsigned* __restrict__ rec, const float* __restrict__ ed,
    const float* __restrict__ bias, float* __restrict__ out, int N)
{
  int wave = (blockIdx.x * TPB + threadIdx.x) >> 6;
  if (wave >= N) return;
  int lane = threadIdx.x & 63;
  int hh = lane & 3, j = lane >> 2;
  int d = wave;
  int e0 = rowptr[d], deg = rowend[d] - e0;
  float edv = ed[d*8 + HOFF + hh];
  float z = 0.f;
  f32x4 acc = {0.f, 0.f, 0.f, 0.f};
  for (int t = j; t <= deg; t += 16) {
    int s = (t == deg) ? d : __builtin_nontemporal_load(col + e0 + t);
    const unsigned* rp = rec + (size_t)s*10;
    unsigned ew = rp[hh >> 1];
    uint2 hv = *(const uint2*)(rp + 2 + 2*hh);
    float esv = ubf((ew >> ((hh & 1) * 16)) & 0xFFFFu);
    float w = __expf(lrelu(esv + edv));
    z += w;
    acc.x += w * ubf(hv.x & 0xFFFFu); acc.y += w * ubf(hv.x >> 16);
    acc.z += w * ubf(hv.y & 0xFFFFu); acc.w += w * ubf(hv.y >> 16);
  }
#pragma unroll
  for (int m = 4; m < 64; m <<= 1) {
    z += __shfl_xor(z, m);
    acc.x += __shfl_xor(acc.x, m); acc.y += __shfl_xor(acc.y, m);
    acc.z += __shfl_xor(acc.z, m); acc.w += __shfl_xor(acc.w, m);
  }
  if (j == 0) {
    float inv = 1.f / z;
    const f32x4 bb = *(const f32x4*)(bias + (HOFF + hh)*4);
    f32x4 o = { acc.x*inv + bb.x, acc.y*inv + bb.y, acc.z*inv + bb.z, acc.w*inv + bb.w };
    __builtin_nontemporal_store(o, (f32x4*)(out + (size_t)d*OS + (HOFF + hh)*4));
  }
}

// Layer 3: 2 heads x 32 slots; 32 B records (3.2 MB, L2-resident), 1 uint4 load.
__global__ void __launch_bounds__(TPB) k_gat3(
    const int* __restrict__ rowptr, const int* __restrict__ rowend, const int* __restrict__ col,
    const unsigned* __restrict__ rec, const float* __restrict__ ed,
    const float* __restrict__ b3, float* __restrict__ x4, int N)
{
  int wave = (blockIdx.x * TPB + threadIdx.x) >> 6;
  if (wave >= N) return;
  int lane = threadIdx.x & 63;
  int hh = lane & 1, j = lane >> 1;
  int d = wave;
  int e0 = rowptr[d], deg = rowend[d] - e0;
  float edv = ed[d*8 + hh];
  float z = 0.f;
  f32x4 acc = {0.f, 0.f, 0.f, 0.f};
  for (int t = j; t <= deg; t += 32) {
    int s = (t == deg) ? d : __builtin_nontemporal_load(col + e0 + t);
    u32x4 q = *(const u32x4*)(rec + (size_t)s*8 + hh*4);
    float w = __expf(lrelu(__uint_as_float(q.x) + edv));
    z += w;
    acc.x += w * ubf(q.y & 0xFFFFu); acc.y += w * ubf(q.y >> 16);
    acc.z += w * ubf(q.z & 0xFFFFu); acc.w += w * ubf(q.z >> 16);
  }
#pragma unroll
  for (int m = 2; m < 64; m <<= 1) {
    z += __shfl_xor(z, m);
    acc.x += __shfl_xor(acc.x, m); acc.y += __shfl_xor(acc.y, m);
    acc.z += __shfl_xor(acc.z, m); acc.w += __shfl_xor(acc.w, m);
  }
  if (j == 0) {
    float inv = 1.f / z;
    const f32x4 bb = *(const f32x4*)(b3 + hh*4);
    f32x4 o = { acc.x*inv + bb.x, acc.y*inv + bb.y, acc.z*inv + bb.z, acc.w*inv + bb.w };
    __builtin_nontemporal_store(o, (f32x4*)(x4 + d*8 + hh*4));
  }
}

__global__ void __launch_bounds__(TPB) k_adj_final(
    const int* __restrict__ rowptr, const int* __restrict__ rowend, const int* __restrict__ col,
    const float* __restrict__ x4, const float* __restrict__ Wl2,
    float* __restrict__ out, int N)
{
  __shared__ float sW[8];
  if (threadIdx.x < 8) sW[threadIdx.x] = Wl2[threadIdx.x];
  __syncthreads();
  int wave = (blockIdx.x * TPB + threadIdx.x) >> 6;
  if (wave >= N) return;
  int lane = threadIdx.x & 63;
  int q = lane & 1, j = lane >> 1;
  int r = wave;
  int e0 = rowptr[N + r], deg = rowend[N + r] - e0;
  f32x4 acc = {0.f, 0.f, 0.f, 0.f};
  for (int t = j; t < deg; t += 32) {
    int c = __builtin_nontemporal_load(col + e0 + t);
    f32x4 xv = *(const f32x4*)(x4 + c*8 + q*4);
    acc.x += xv.x; acc.y += xv.y; acc.z += xv.z; acc.w += xv.w;
  }
#pragma unroll
  for (int m = 2; m < 64; m <<= 1) {
    acc.x += __shfl_xor(acc.x, m); acc.y += __shfl_xor(acc.y, m);
    acc.z += __shfl_xor(acc.z, m); acc.w += __shfl_xor(acc.w, m);
  }
  float part = 0.f;
  if (j == 0) {
    float inv = deg > 0 ? 1.f / (float)deg : 0.f;
    f32x4 R = { acc.x*inv, acc.y*inv, acc.z*inv, acc.w*inv };
    f32x4 xo = *(const f32x4*)(x4 + r*8 + q*4);
    part = xo.x*R.x + xo.y*R.y + xo.z*R.z + xo.w*R.w
         + R.x*sW[q*4+0] + R.y*sW[q*4+1] + R.z*sW[q*4+2] + R.w*sW[q*4+3];
  }
  part += __shfl_xor(part, 1);
  if (lane == 0) out[r] = part;
}

// ============================ launch ========================================
extern "C" void kernel_launch(void* const* d_in, const int* in_sizes, int n_in,
                              void* d_out, int out_size, void* d_ws, size_t ws_size,
                              hipStream_t stream)
{
  const float* x1  = (const float*)d_in[0];
  const float* x2  = (const float*)d_in[1];
  const int*   ei  = (const int*)d_in[2];
  const float* Wq  = (const float*)d_in[4];
  const float* bq  = (const float*)d_in[5];
  const float* Wk  = (const float*)d_in[6];
  const float* bk  = (const float*)d_in[7];
  const float* Wv  = (const float*)d_in[8];
  const float* bv  = (const float*)d_in[9];
  const float* W1  = (const float*)d_in[10];
  const float* a1s = (const float*)d_in[11];
  const float* a1d = (const float*)d_in[12];
  const float* b1  = (const float*)d_in[13];
  const float* W2  = (const float*)d_in[14];
  const float* a2s = (const float*)d_in[15];
  const float* a2d = (const float*)d_in[16];
  const float* b2  = (const float*)d_in[17];
  const float* W3  = (const float*)d_in[18];
  const float* a3s = (const float*)d_in[19];
  const float* a3d = (const float*)d_in[20];
  const float* b3  = (const float*)d_in[21];
  const float* Wl2 = (const float*)d_in[22];

  int N = in_sizes[0] / 8;
  int E = in_sizes[2] / 2;
  int n2 = 2 * N;
  int NB = (n2 + 255) >> 8;             // CSR buckets (782)
  int gB = (E + EPB - 1) / EPB;         // k_bucket blocks (782)

  // ---- workspace ----
  float* sumexp = (float*)d_ws;                          // 16 (1 used, zeroed)
  int* rowptr   = (int*)(sumexp + 16);                   // 2N
  int* rowend   = rowptr + (size_t)n2;                   // 2N
  unsigned* itemsCSR = (unsigned*)(rowend + (size_t)n2); // NB*CAP (28.8 MB)
  unsigned* regionA  = itemsCSR + (size_t)NB * CAP;
  // phase 1 (CSR build): items2 + ofs + ofsT live in regionA
  unsigned* items2 = regionA;                            // gB*8192 (25.6 MB)
  int* ofs  = (int*)(items2 + (size_t)gB * (2 * EPB));   // gB*OFSW
  int* ofsT = ofs + (size_t)gB * OFSW;                   // OFSW*GBPAD
  size_t raSize = (size_t)gB * (2 * EPB + OFSW) + (size_t)OFSW * GBPAD;
  // phase 2: recs/ed/escore alias regionA (items2/ofs dead). 10N*3+8N+8N+N = 47N < raSize ✓
  unsigned* rec1a = regionA;                             // 10N (4.0 MB, L2-resident)
  unsigned* rec1b = rec1a + 10ull*N;                     // 10N (aliased by x4 later)
  unsigned* rec2  = rec1b + 10ull*N;                     // 10N
  unsigned* rec3  = rec2 + 10ull*N;                      // 8N (3.2 MB)
  float* ed       = (float*)(rec3 + 8ull*N);             // 8N
  float* escore   = ed + 8ull*N;                         // N
  float* X        = (float*)(regionA + raSize);          // 32N (X3 aliases, stride 16)
  float* X3 = X;
  float* x4 = (float*)rec1b;                             // 8N (rec1b dead by then)

  int gN = (N + TPB - 1) / TPB;
  int g64 = (int)(((long long)N * 64 + TPB - 1) / TPB);  // wave-per-row grids

  (void)hipMemsetAsync(sumexp, 0, 16 * sizeof(float), stream);

  // CSR build
  k_bucket<<<gB, TPB, 0, stream>>>(ei, E, N, items2, ofs);
  dim3 gt((OFSW + 31) / 32, (gB + 31) / 32);
  k_t<<<gt, TPB, 0, stream>>>(ofs, ofsT, gB);
  k_csr2<<<NB, TPB, 0, stream>>>(ofsT, items2, gB, itemsCSR, rowptr, rowend, n2);
  int* colv = (int*)itemsCSR;

  // dense prologue
  k_score<<<gN, TPB, 0, stream>>>(x1, x2, Wq, bq, Wk, bk, escore, sumexp, N);
  k_A1<<<gN, TPB, 0, stream>>>(x1, x2, Wv, bv, W1, a1s, a1d, escore, sumexp, rec1a, rec1b, ed, N);

  // GAT layer 1 (two 4-head passes over L2-resident 4 MB records)
  k_gat4<32, 0><<<g64, TPB, 0, stream>>>(rowptr, rowend, colv, rec1a, ed, b1, X, N);
  k_gat4<32, 4><<<g64, TPB, 0, stream>>>(rowptr, rowend, colv, rec1b, ed, b1, X, N);
  // GAT layer 2
  k_B2<<<gN, TPB, 0, stream>>>(W2, a2s, a2d, X, rec2, ed, N);
  k_gat4<16, 0><<<g64, TPB, 0, stream>>>(rowptr, rowend, colv, rec2, ed, b2, X3, N);
  // GAT layer 3
  k_B3<<<gN, TPB, 0, stream>>>(W3, a3s, a3d, X3, rec3, ed, N);
  k_gat3<<<g64, TPB, 0, stream>>>(rowptr, rowend, colv, rec3, ed, b3, x4, N);

  // adjacency readout (src-CSR rows [N,2N))
  k_adj_final<<<g64, TPB, 0, stream>>>(rowptr, rowend, colv, x4, Wl2, (float*)d_out, N);
}